// Round 1
// baseline (6125.953 us; speedup 1.0000x reference)
//
#include <hip/hip_runtime.h>

#define NIMG 4
#define C    256
#define H    128
#define W    128
#define HW   (H*W)         // 16384
#define CHW  (C*HW)        // 4194304
#define TOT  (NIMG*CHW)    // 16777216 elems per output tensor

// ---------------------------------------------------------------------------
// K1: compressed = w_comp(256x256) @ x + b_comp   (1x1 conv)
// grid (NIMG*H pos-tiles of one full row, 4 co-tiles), block 256
// tile: 64 co x 128 x-positions, K=256 in chunks of 32, micro 4x8
// ---------------------------------------------------------------------------
__global__ __launch_bounds__(256)
void conv1x1_kernel(const float* __restrict__ x, const float* __restrict__ w,
                    const float* __restrict__ b, float* __restrict__ out)
{
    __shared__ float As[32][64];
    __shared__ float Bs[32][128];

    const int pt  = blockIdx.x;        // n*H + y
    const int n   = pt >> 7;
    const int y   = pt & 127;
    const int co0 = blockIdx.y * 64;
    const int tid = threadIdx.x;
    const int tco = tid >> 4;          // 0..15
    const int tps = tid & 15;          // 0..15

    float acc[4][8];
    #pragma unroll
    for (int i = 0; i < 4; ++i)
        #pragma unroll
        for (int j = 0; j < 8; ++j) acc[i][j] = 0.f;

    const float* xrow = x + n*CHW + y*W;

    for (int c0 = 0; c0 < 256; c0 += 32) {
        #pragma unroll
        for (int r = 0; r < 8; ++r) {          // A: 32k x 64co
            int l = tid + 256*r;
            int coi = l & 63, k = l >> 6;
            As[k][coi] = w[(co0+coi)*256 + c0 + k];
        }
        #pragma unroll
        for (int r = 0; r < 16; ++r) {         // B: 32k x 128x
            int l = tid + 256*r;
            int xc = l & 127, k = l >> 7;
            Bs[k][xc] = xrow[(c0+k)*HW + xc];
        }
        __syncthreads();
        #pragma unroll 8
        for (int k = 0; k < 32; ++k) {
            float av[4], bv[8];
            #pragma unroll
            for (int i = 0; i < 4; ++i) av[i] = As[k][tco*4+i];
            #pragma unroll
            for (int j = 0; j < 8; ++j) bv[j] = Bs[k][tps*8+j];
            #pragma unroll
            for (int i = 0; i < 4; ++i)
                #pragma unroll
                for (int j = 0; j < 8; ++j)
                    acc[i][j] += av[i]*bv[j];
        }
        __syncthreads();
    }

    #pragma unroll
    for (int i = 0; i < 4; ++i) {
        int co = co0 + tco*4 + i;
        float bias = b[co];
        float* orow = out + n*CHW + co*HW + y*W + tps*8;
        #pragma unroll
        for (int j = 0; j < 8; ++j) orow[j] = acc[i][j] + bias;
    }
}

// ---------------------------------------------------------------------------
// K2: fused 3x3 convs over compressed.
// co-space: tile 0 -> hp (9 valid co, write raw filt to ws)
//           tiles 1..4 -> res (feat_add = x + v), 5..8 -> mul (feat_mul = x*v)
// Implicit GEMM: K = 256ci x 9taps, chunked 16ci per stage.
// tile: 64co x 128pos (one full image row), micro 4x8.
// ---------------------------------------------------------------------------
__global__ __launch_bounds__(256)
void conv3x3_fused_kernel(const float* __restrict__ comp,
                          const float* __restrict__ xin,
                          const float* __restrict__ w_hp,  const float* __restrict__ b_hp,
                          const float* __restrict__ w_res, const float* __restrict__ b_res,
                          const float* __restrict__ w_mul, const float* __restrict__ b_mul,
                          float* __restrict__ out, float* __restrict__ filt_raw)
{
    __shared__ float As[16][9][64];    // [ci][tap][co]   36,864 B
    __shared__ float Bp[16][3][132];   // [ci][kh][x+pad] 25,344 B

    const int pt = blockIdx.x;         // n*H + y
    const int n  = pt >> 7;
    const int y  = pt & 127;
    const int ct = blockIdx.y;         // 0..8

    const float *wptr, *bptr;
    int mode, col0, covalid;
    if (ct == 0)      { wptr = w_hp;  bptr = b_hp;  mode = 0; col0 = 0;          covalid = 9;  }
    else if (ct <= 4) { wptr = w_res; bptr = b_res; mode = 1; col0 = (ct-1)*64;  covalid = 64; }
    else              { wptr = w_mul; bptr = b_mul; mode = 2; col0 = (ct-5)*64;  covalid = 64; }

    const int tid = threadIdx.x;
    const int tco = tid >> 4;          // 0..15
    const int tps = tid & 15;          // 0..15

    float acc[4][8];
    #pragma unroll
    for (int i = 0; i < 4; ++i)
        #pragma unroll
        for (int j = 0; j < 8; ++j) acc[i][j] = 0.f;

    float* AsF = &As[0][0][0];
    float* BpF = &Bp[0][0][0];

    for (int c0 = 0; c0 < 256; c0 += 16) {
        // ---- stage A: w[col0+coi][c0+k][t] -> As[k][t][coi]  (9216 elems)
        #pragma unroll
        for (int r = 0; r < 36; ++r) {
            int l   = tid + 256*r;
            int coi = l & 63;
            int kt  = l >> 6;          // 0..143
            int k   = kt / 9;
            int t   = kt - k*9;
            float v = 0.f;
            if (coi < covalid)
                v = wptr[(col0+coi)*2304 + (c0+k)*9 + t];
            AsF[l] = v;
        }
        // ---- stage B: comp patch rows y-1..y+1, cols -1..129 -> Bp (6336 slots)
        #pragma unroll
        for (int r = 0; r < 25; ++r) {
            int l = tid + 256*r;
            if (l < 16*3*132) {
                int k   = l / 396;
                int rem = l - k*396;
                int kh  = rem / 132;
                int cx  = rem - kh*132;
                int yy  = y + kh - 1;
                float v = 0.f;
                if (cx >= 1 && cx <= 128 && yy >= 0 && yy < 128)
                    v = comp[n*CHW + (c0+k)*HW + yy*W + (cx-1)];
                BpF[l] = v;
            }
        }
        __syncthreads();

        // ---- compute
        #pragma unroll 2
        for (int k = 0; k < 16; ++k) {
            #pragma unroll
            for (int kh = 0; kh < 3; ++kh) {
                float bl[10];
                #pragma unroll
                for (int j = 0; j < 10; ++j) bl[j] = Bp[k][kh][tps*8 + j];
                #pragma unroll
                for (int kw = 0; kw < 3; ++kw) {
                    float av[4];
                    #pragma unroll
                    for (int i = 0; i < 4; ++i) av[i] = As[k][kh*3+kw][tco*4 + i];
                    #pragma unroll
                    for (int i = 0; i < 4; ++i)
                        #pragma unroll
                        for (int j = 0; j < 8; ++j)
                            acc[i][j] += av[i]*bl[j+kw];
                }
            }
        }
        __syncthreads();
    }

    // ---- epilogue
    const int xb = tps*8;
    #pragma unroll
    for (int i = 0; i < 4; ++i) {
        int coi = tco*4 + i;
        if (coi >= covalid) continue;
        float bias = bptr[col0 + coi];
        if (mode == 0) {
            float* f = filt_raw + (n*9 + coi)*HW + y*W + xb;
            #pragma unroll
            for (int j = 0; j < 8; ++j) f[j] = acc[i][j] + bias;
        } else {
            int c = col0 + coi;
            long idx = (long)n*CHW + (long)c*HW + y*W + xb;
            const float* xr = xin + idx;
            float* o = out + (mode == 1 ? (long)TOT : (long)2*TOT) + idx;
            #pragma unroll
            for (int j = 0; j < 8; ++j) {
                float v = acc[i][j] + bias;
                o[j] = (mode == 1) ? (xr[j] + v) : (xr[j] * v);
            }
        }
    }
}

// ---------------------------------------------------------------------------
// K3: normalize filt (softmax*hamming, renorm == e*h/sum(e*h)),
//     carafe 3x3 over x, feat_hp = x - carafe.
// grid NIMG*H, block 256: lane = x (0..127), tid>>7 = channel half
// ---------------------------------------------------------------------------
__global__ __launch_bounds__(256)
void carafe_hp_kernel(const float* __restrict__ x, const float* __restrict__ filt_raw,
                      const float* __restrict__ ham, float* __restrict__ out)
{
    const int pt = blockIdx.x;
    const int n  = pt >> 7;
    const int y  = pt & 127;
    const int xi = threadIdx.x & 127;
    const int ch = threadIdx.x >> 7;     // 0 or 1

    float f[9];
    const float* fr = filt_raw + n*9*HW + y*W + xi;
    float m = -1e30f;
    #pragma unroll
    for (int t = 0; t < 9; ++t) { f[t] = fr[t*HW]; m = fmaxf(m, f[t]); }
    float s = 0.f;
    #pragma unroll
    for (int t = 0; t < 9; ++t) { f[t] = expf(f[t]-m) * ham[t]; s += f[t]; }
    float inv = 1.f / s;
    #pragma unroll
    for (int t = 0; t < 9; ++t) f[t] *= inv;

    for (int cc = 0; cc < 128; ++cc) {
        int c = ch*128 + cc;
        const float* xc = x + (long)n*CHW + (long)c*HW;
        float sum = 0.f;
        #pragma unroll
        for (int dh = -1; dh <= 1; ++dh) {
            int yy = y + dh;
            if (yy < 0 || yy >= H) continue;
            #pragma unroll
            for (int dw = -1; dw <= 1; ++dw) {
                int xx = xi + dw;
                if (xx < 0 || xx >= W) continue;
                sum += f[(dh+1)*3 + (dw+1)] * xc[yy*W + xx];
            }
        }
        out[(long)n*CHW + (long)c*HW + y*W + xi] = xc[y*W + xi] - sum;
    }
}

// ---------------------------------------------------------------------------
extern "C" void kernel_launch(void* const* d_in, const int* in_sizes, int n_in,
                              void* d_out, int out_size, void* d_ws, size_t ws_size,
                              hipStream_t stream)
{
    const float* x      = (const float*)d_in[0];
    const float* w_comp = (const float*)d_in[1];
    const float* b_comp = (const float*)d_in[2];
    const float* w_hp   = (const float*)d_in[3];
    const float* b_hp   = (const float*)d_in[4];
    const float* w_res  = (const float*)d_in[5];
    const float* b_res  = (const float*)d_in[6];
    const float* w_mul  = (const float*)d_in[7];
    const float* b_mul  = (const float*)d_in[8];
    const float* ham    = (const float*)d_in[9];
    float* out  = (float*)d_out;

    float* comp = (float*)d_ws;          // 16,777,216 f32 = 64 MB
    float* filt = comp + TOT;            //    589,824 f32 = 2.25 MB

    conv1x1_kernel<<<dim3(NIMG*H, 4), 256, 0, stream>>>(x, w_comp, b_comp, comp);
    conv3x3_fused_kernel<<<dim3(NIMG*H, 9), 256, 0, stream>>>(
        comp, x, w_hp, b_hp, w_res, b_res, w_mul, b_mul, out, filt);
    carafe_hp_kernel<<<NIMG*H, 256, 0, stream>>>(x, filt, ham, out);
}

// Round 3
// 730.433 us; speedup vs baseline: 8.3867x; 8.3867x over previous
//
#include <hip/hip_runtime.h>
#include <hip/hip_bf16.h>

#define NIMG 4
#define C    256
#define H    128
#define W    128
#define HW   (H*W)         // 16384
#define CHW  (C*HW)        // 4194304
#define TOT  (NIMG*CHW)    // 16777216 elems per output tensor

typedef short bf16x8 __attribute__((ext_vector_type(8)));
typedef float f32x16 __attribute__((ext_vector_type(16)));
typedef unsigned short u16;

__device__ inline u16 f2bf(float f) {
    __hip_bfloat16 h = __float2bfloat16(f);
    return __builtin_bit_cast(u16, h);
}

// ---------------------------------------------------------------------------
// prep: concat + bf16-convert weights: wcat[576 co][tap*256 + ci]  (tap-major!)
// co 0..8 = hp, 9..264 = res, 265..520 = mul, 521..575 = zero pad
// ---------------------------------------------------------------------------
__global__ __launch_bounds__(256)
void prep_w_kernel(const float* __restrict__ w_hp, const float* __restrict__ w_res,
                   const float* __restrict__ w_mul, u16* __restrict__ wcat)
{
    int i = blockIdx.x * 256 + threadIdx.x;
    if (i >= 576 * 2304) return;
    int co = i / 2304, r = i - co * 2304;
    int tap = r >> 8, ci = r & 255;          // dst k = tap*256 + ci
    float v = 0.f;
    if (co < 9)        v = w_hp[co * 2304 + ci * 9 + tap];
    else if (co < 265) v = w_res[(co - 9) * 2304 + ci * 9 + tap];
    else if (co < 521) v = w_mul[(co - 265) * 2304 + ci * 9 + tap];
    wcat[i] = f2bf(v);
}

// ---------------------------------------------------------------------------
// K1: compressed(bf16) = w_comp(256x256) @ x + b_comp   (1x1 conv)
// ---------------------------------------------------------------------------
__global__ __launch_bounds__(256)
void conv1x1_kernel(const float* __restrict__ x, const float* __restrict__ w,
                    const float* __restrict__ b, u16* __restrict__ out)
{
    __shared__ float As[32][64];
    __shared__ float Bs[32][128];

    const int pt  = blockIdx.x;        // n*H + y
    const int n   = pt >> 7;
    const int y   = pt & 127;
    const int co0 = blockIdx.y * 64;
    const int tid = threadIdx.x;
    const int tco = tid >> 4;
    const int tps = tid & 15;

    float acc[4][8];
    #pragma unroll
    for (int i = 0; i < 4; ++i)
        #pragma unroll
        for (int j = 0; j < 8; ++j) acc[i][j] = 0.f;

    const float* xrow = x + n*CHW + y*W;

    for (int c0 = 0; c0 < 256; c0 += 32) {
        #pragma unroll
        for (int r = 0; r < 8; ++r) {
            int l = tid + 256*r;
            int coi = l & 63, k = l >> 6;
            As[k][coi] = w[(co0+coi)*256 + c0 + k];
        }
        #pragma unroll
        for (int r = 0; r < 16; ++r) {
            int l = tid + 256*r;
            int xc = l & 127, k = l >> 7;
            Bs[k][xc] = xrow[(c0+k)*HW + xc];
        }
        __syncthreads();
        #pragma unroll 8
        for (int k = 0; k < 32; ++k) {
            float av[4], bv[8];
            #pragma unroll
            for (int i = 0; i < 4; ++i) av[i] = As[k][tco*4+i];
            #pragma unroll
            for (int j = 0; j < 8; ++j) bv[j] = Bs[k][tps*8+j];
            #pragma unroll
            for (int i = 0; i < 4; ++i)
                #pragma unroll
                for (int j = 0; j < 8; ++j)
                    acc[i][j] += av[i]*bv[j];
        }
        __syncthreads();
    }

    #pragma unroll
    for (int i = 0; i < 4; ++i) {
        int co = co0 + tco*4 + i;
        float bias = b[co];
        u16* orow = out + (long)n*CHW + (long)co*HW + y*W + tps*8;
        ushort4 lo = make_ushort4(f2bf(acc[i][0]+bias), f2bf(acc[i][1]+bias),
                                  f2bf(acc[i][2]+bias), f2bf(acc[i][3]+bias));
        ushort4 hi = make_ushort4(f2bf(acc[i][4]+bias), f2bf(acc[i][5]+bias),
                                  f2bf(acc[i][6]+bias), f2bf(acc[i][7]+bias));
        *(ushort4*)(orow)     = lo;
        *(ushort4*)(orow + 4) = hi;
    }
}

// ---------------------------------------------------------------------------
// K2: fused 3x3 convs via bf16 MFMA implicit GEMM.
// block: 64 co x 512 pos (4 image rows), 4 waves (each 64co x 128pos = 1 row)
// K = 256 ci x 9 taps, chunk = 16 ci.
// LDS: As[64co][152]  ([tap][ci]: tap*16+ci, 144 valid +8 pad)
//      Bs[6 row][132 col][24ci pad]  (16 valid ci)
// ---------------------------------------------------------------------------
__global__ __launch_bounds__(256, 2)
void conv3x3_mfma_kernel(const u16* __restrict__ comp, const u16* __restrict__ wcat,
                         const float* __restrict__ xin,
                         const float* __restrict__ b_hp, const float* __restrict__ b_res,
                         const float* __restrict__ b_mul,
                         float* __restrict__ out, float* __restrict__ filt_raw)
{
    __shared__ u16 As[64 * 152];         // 19,456 B
    __shared__ u16 Bs[6 * 132 * 24];     // 38,016 B

    const int pt  = blockIdx.x;          // 0..127
    const int n   = pt >> 5;
    const int y0  = (pt & 31) * 4;
    const int co0 = blockIdx.y * 64;     // 0..8 tiles

    const int tid  = threadIdx.x;
    const int wv   = tid >> 6;           // wave 0..3 -> image row y0+wv
    const int lane = tid & 63;
    const int l31  = lane & 31;
    const int lh   = lane >> 5;          // k-group

    // zero Bs once (borders & oob rows stay zero across chunks)
    for (int i = tid; i < 6*132*24/2; i += 256) ((int*)Bs)[i] = 0;
    __syncthreads();

    f32x16 acc[2][4];
    #pragma unroll
    for (int cf = 0; cf < 2; ++cf)
        #pragma unroll
        for (int p = 0; p < 4; ++p)
            #pragma unroll
            for (int e = 0; e < 16; ++e) acc[cf][p][e] = 0.f;

    const u16* wbase = wcat + (long)co0 * 2304;

    for (int c0 = 0; c0 < 256; c0 += 16) {
        // ---- stage A: per (co,tap): 16 ci starting at c0 -> As[co][tap*16..+15]
        // item l (0..2303): co = l/36, u = l%36: tap = u>>2, ciq = u&3
        #pragma unroll
        for (int r = 0; r < 9; ++r) {
            int l   = tid + 256*r;
            int co  = l / 36, u = l - co*36;
            int tap = u >> 2, ciq = u & 3;
            ushort4 v = *(const ushort4*)(wbase + co*2304 + tap*256 + c0 + ciq*4);
            *(ushort4*)(As + co*152 + tap*16 + ciq*4) = v;
        }
        // ---- stage B: 16ci x 6rows x 128cols, transposed to [row][col][ci]
        #pragma unroll
        for (int rr = 0; rr < 3; ++rr) {
            int l = tid + 256*rr;        // 0..767
            int q = l & 3, t = l >> 2;
            int r = t >> 5, g = t & 31;
            int yy = y0 - 1 + r;
            if (yy >= 0 && yy < H) {
                int x0 = g * 4;
                const u16* src = comp + ((long)(n*C + c0 + q*4) * HW) + yy*W + x0;
                ushort4 v0 = *(const ushort4*)(src);
                ushort4 v1 = *(const ushort4*)(src + HW);
                ushort4 v2 = *(const ushort4*)(src + 2*HW);
                ushort4 v3 = *(const ushort4*)(src + 3*HW);
                u16* dst = Bs + (r*132 + x0 + 1)*24 + q*4;
                *(ushort4*)(dst)      = make_ushort4(v0.x, v1.x, v2.x, v3.x);
                *(ushort4*)(dst + 24) = make_ushort4(v0.y, v1.y, v2.y, v3.y);
                *(ushort4*)(dst + 48) = make_ushort4(v0.z, v1.z, v2.z, v3.z);
                *(ushort4*)(dst + 72) = make_ushort4(v0.w, v1.w, v2.w, v3.w);
            }
        }
        __syncthreads();

        // ---- MFMA: per tap: 2 A-frags, 4 B-frags, 8 MFMA
        #pragma unroll
        for (int tap = 0; tap < 9; ++tap) {
            const int kh = tap / 3, kw = tap - kh*3;
            bf16x8 a0 = *(const bf16x8*)(As + (l31      )*152 + tap*16 + lh*8);
            bf16x8 a1 = *(const bf16x8*)(As + (l31 + 32 )*152 + tap*16 + lh*8);
            #pragma unroll
            for (int p = 0; p < 4; ++p) {
                bf16x8 b = *(const bf16x8*)(Bs + ((wv+kh)*132 + p*32 + l31 + kw)*24 + lh*8);
                acc[0][p] = __builtin_amdgcn_mfma_f32_32x32x16_bf16(a0, b, acc[0][p], 0, 0, 0);
                acc[1][p] = __builtin_amdgcn_mfma_f32_32x32x16_bf16(a1, b, acc[1][p], 0, 0, 0);
            }
        }
        __syncthreads();
    }

    // ---- epilogue: D col = lane&31 (pos), row = (reg&3)+8*(reg>>2)+4*(lane>>5) (co)
    const int yrow = y0 + wv;
    #pragma unroll
    for (int cf = 0; cf < 2; ++cf) {
        #pragma unroll
        for (int p = 0; p < 4; ++p) {
            #pragma unroll
            for (int reg = 0; reg < 16; ++reg) {
                int row = (reg & 3) + 8*(reg >> 2) + 4*lh;
                int co  = co0 + cf*32 + row;
                int xx  = p*32 + l31;
                float v = acc[cf][p][reg];
                if (co < 9) {
                    filt_raw[((long)n*9 + co)*HW + yrow*W + xx] = v + b_hp[co];
                } else if (co < 265) {
                    int c = co - 9;
                    long idx = (long)n*CHW + (long)c*HW + yrow*W + xx;
                    out[(long)TOT + idx] = xin[idx] + v + b_res[c];
                } else if (co < 521) {
                    int c = co - 265;
                    long idx = (long)n*CHW + (long)c*HW + yrow*W + xx;
                    out[2L*TOT + idx] = xin[idx] * (v + b_mul[c]);
                }
            }
        }
    }
}

// ---------------------------------------------------------------------------
// K3: softmax*hamming renorm + 3x3 carafe + feat_hp = x - carafe
// ---------------------------------------------------------------------------
__global__ __launch_bounds__(256)
void carafe_hp_kernel(const float* __restrict__ x, const float* __restrict__ filt_raw,
                      const float* __restrict__ ham, float* __restrict__ out)
{
    const int pt = blockIdx.x;
    const int n  = pt >> 7;
    const int y  = pt & 127;
    const int xi = threadIdx.x & 127;
    const int ch = threadIdx.x >> 7;

    float f[9];
    const float* fr = filt_raw + n*9*HW + y*W + xi;
    float m = -1e30f;
    #pragma unroll
    for (int t = 0; t < 9; ++t) { f[t] = fr[t*HW]; m = fmaxf(m, f[t]); }
    float s = 0.f;
    #pragma unroll
    for (int t = 0; t < 9; ++t) { f[t] = expf(f[t]-m) * ham[t]; s += f[t]; }
    float inv = 1.f / s;
    #pragma unroll
    for (int t = 0; t < 9; ++t) f[t] *= inv;

    for (int cc = 0; cc < 128; ++cc) {
        int c = ch*128 + cc;
        const float* xc = x + (long)n*CHW + (long)c*HW;
        float sum = 0.f;
        #pragma unroll
        for (int dh = -1; dh <= 1; ++dh) {
            int yy = y + dh;
            if (yy < 0 || yy >= H) continue;
            #pragma unroll
            for (int dw = -1; dw <= 1; ++dw) {
                int xx = xi + dw;
                if (xx < 0 || xx >= W) continue;
                sum += f[(dh+1)*3 + (dw+1)] * xc[yy*W + xx];
            }
        }
        out[(long)n*CHW + (long)c*HW + y*W + xi] = xc[y*W + xi] - sum;
    }
}

// ---------------------------------------------------------------------------
extern "C" void kernel_launch(void* const* d_in, const int* in_sizes, int n_in,
                              void* d_out, int out_size, void* d_ws, size_t ws_size,
                              hipStream_t stream)
{
    const float* x      = (const float*)d_in[0];
    const float* w_comp = (const float*)d_in[1];
    const float* b_comp = (const float*)d_in[2];
    const float* w_hp   = (const float*)d_in[3];
    const float* b_hp   = (const float*)d_in[4];
    const float* w_res  = (const float*)d_in[5];
    const float* b_res  = (const float*)d_in[6];
    const float* w_mul  = (const float*)d_in[7];
    const float* b_mul  = (const float*)d_in[8];
    const float* ham    = (const float*)d_in[9];
    float* out = (float*)d_out;

    u16*   comp = (u16*)d_ws;                                  // TOT*2   = 33,554,432 B
    float* filt = (float*)((char*)d_ws + (size_t)TOT*2);       // 589,824*4 = 2,359,296 B
    u16*   wcat = (u16*)((char*)d_ws + (size_t)TOT*2 + 2359296); // 576*2304*2 = 2,654,208 B

    prep_w_kernel<<<(576*2304 + 255)/256, 256, 0, stream>>>(w_hp, w_res, w_mul, wcat);
    conv1x1_kernel<<<dim3(NIMG*H, 4), 256, 0, stream>>>(x, w_comp, b_comp, comp);
    conv3x3_mfma_kernel<<<dim3(NIMG*H/4, 9), 256, 0, stream>>>(
        comp, wcat, x, b_hp, b_res, b_mul, out, filt);
    carafe_hp_kernel<<<NIMG*H, 256, 0, stream>>>(x, filt, ham, out);
}

// Round 4
// 375.650 us; speedup vs baseline: 16.3076x; 1.9445x over previous
//
#include <hip/hip_runtime.h>
#include <hip/hip_bf16.h>

#define NIMG 4
#define C    256
#define H    128
#define W    128
#define HW   (H*W)         // 16384
#define CHW  (C*HW)        // 4194304
#define TOT  (NIMG*CHW)    // 16777216 elems per output tensor

typedef short bf16x8 __attribute__((ext_vector_type(8)));
typedef float f32x16 __attribute__((ext_vector_type(16)));
typedef unsigned short u16;

__device__ inline u16 f2bf(float f) {
    __hip_bfloat16 h = __float2bfloat16(f);
    return __builtin_bit_cast(u16, h);
}

// ---------------------------------------------------------------------------
// prep: wcat[576 co][tap*256+ci] (tap-major) from hp/res/mul; wbf = bf16(w_comp)
// ---------------------------------------------------------------------------
__global__ __launch_bounds__(256)
void prep_w_kernel(const float* __restrict__ w_hp, const float* __restrict__ w_res,
                   const float* __restrict__ w_mul, const float* __restrict__ w_comp,
                   u16* __restrict__ wcat, u16* __restrict__ wbf)
{
    int i = blockIdx.x * 256 + threadIdx.x;
    const int NW = 576 * 2304;
    if (i < NW) {
        int co = i / 2304, r = i - co * 2304;
        int tap = r >> 8, ci = r & 255;
        float v = 0.f;
        if (co < 9)        v = w_hp[co * 2304 + ci * 9 + tap];
        else if (co < 265) v = w_res[(co - 9) * 2304 + ci * 9 + tap];
        else if (co < 521) v = w_mul[(co - 265) * 2304 + ci * 9 + tap];
        wcat[i] = f2bf(v);
    } else if (i < NW + 65536) {
        int j = i - NW;
        wbf[j] = f2bf(w_comp[j]);
    }
}

// ---------------------------------------------------------------------------
// K1: compressed(bf16) = w_comp @ x + b_comp via bf16 MFMA.
// block: 64 co x 256 pos, 4 waves (each 64co x 64pos, acc[2][2]).
// K = 256 ci, chunk 32. LDS: As[64][40], Bs[256][40] (pad 40 u16 = 4-way ok)
// ---------------------------------------------------------------------------
__global__ __launch_bounds__(256)
void conv1x1_mfma_kernel(const float* __restrict__ x, const u16* __restrict__ wbf,
                         const float* __restrict__ b, u16* __restrict__ comp)
{
    __shared__ u16 As[64 * 40];      //  5,120 B
    __shared__ u16 Bs[256 * 40];     // 20,480 B

    const int pt  = blockIdx.x;          // 0..255
    const int n   = pt >> 6;
    const int hw0 = (pt & 63) * 256;
    const int co0 = blockIdx.y * 64;

    const int tid  = threadIdx.x;
    const int wv   = tid >> 6;
    const int lane = tid & 63;
    const int l31  = lane & 31;
    const int lh   = lane >> 5;

    f32x16 acc[2][2];
    #pragma unroll
    for (int cf = 0; cf < 2; ++cf)
        #pragma unroll
        for (int p = 0; p < 2; ++p)
            #pragma unroll
            for (int e = 0; e < 16; ++e) acc[cf][p][e] = 0.f;

    for (int c0 = 0; c0 < 256; c0 += 32) {
        // A: 64co x 32ci. item l = tid+256r (r<2): co=l>>3, cq=l&7
        #pragma unroll
        for (int r = 0; r < 2; ++r) {
            int l  = tid + 256*r;
            int co = l >> 3, cq = l & 7;
            ushort4 v = *(const ushort4*)(wbf + (co0+co)*256 + c0 + cq*4);
            *(ushort4*)(As + co*40 + cq*4) = v;
        }
        // B: 256pos x 32ci (fp32 -> bf16, transposed). item: q=l&7 (ci grp), g=l>>3 (pos grp)
        #pragma unroll
        for (int r = 0; r < 2; ++r) {
            int l = tid + 256*r;
            int q = l & 7, g = l >> 3;
            const float* src = x + (long)n*CHW + (long)(c0 + q*4)*HW + hw0 + g*4;
            float4 v0 = *(const float4*)(src);
            float4 v1 = *(const float4*)(src + HW);
            float4 v2 = *(const float4*)(src + 2*HW);
            float4 v3 = *(const float4*)(src + 3*HW);
            u16* dst = Bs + (g*4)*40 + q*4;
            *(ushort4*)(dst)       = make_ushort4(f2bf(v0.x), f2bf(v1.x), f2bf(v2.x), f2bf(v3.x));
            *(ushort4*)(dst + 40)  = make_ushort4(f2bf(v0.y), f2bf(v1.y), f2bf(v2.y), f2bf(v3.y));
            *(ushort4*)(dst + 80)  = make_ushort4(f2bf(v0.z), f2bf(v1.z), f2bf(v2.z), f2bf(v3.z));
            *(ushort4*)(dst + 120) = make_ushort4(f2bf(v0.w), f2bf(v1.w), f2bf(v2.w), f2bf(v3.w));
        }
        __syncthreads();
        #pragma unroll
        for (int kk = 0; kk < 2; ++kk) {
            bf16x8 a0 = *(const bf16x8*)(As + (l31     )*40 + kk*16 + lh*8);
            bf16x8 a1 = *(const bf16x8*)(As + (l31 + 32)*40 + kk*16 + lh*8);
            #pragma unroll
            for (int p = 0; p < 2; ++p) {
                bf16x8 bb = *(const bf16x8*)(Bs + (wv*64 + p*32 + l31)*40 + kk*16 + lh*8);
                acc[0][p] = __builtin_amdgcn_mfma_f32_32x32x16_bf16(a0, bb, acc[0][p], 0, 0, 0);
                acc[1][p] = __builtin_amdgcn_mfma_f32_32x32x16_bf16(a1, bb, acc[1][p], 0, 0, 0);
            }
        }
        __syncthreads();
    }

    // epilogue: col = pos, row = co (same mapping as K2, verified)
    #pragma unroll
    for (int cf = 0; cf < 2; ++cf) {
        #pragma unroll
        for (int p = 0; p < 2; ++p) {
            int pos = hw0 + wv*64 + p*32 + l31;
            #pragma unroll
            for (int reg = 0; reg < 16; ++reg) {
                int row = (reg & 3) + 8*(reg >> 2) + 4*lh;
                int co  = co0 + cf*32 + row;
                comp[(long)n*CHW + (long)co*HW + pos] = f2bf(acc[cf][p][reg] + b[co]);
            }
        }
    }
}

// ---------------------------------------------------------------------------
// K2: fused 3x3 convs via bf16 MFMA implicit GEMM, B-stage register-prefetched.
// block: 64 co x 512 pos (4 rows), 4 waves. K = 256ci x 9taps, chunk 16 ci.
// ---------------------------------------------------------------------------
__global__ __launch_bounds__(256, 2)
void conv3x3_mfma_kernel(const u16* __restrict__ comp, const u16* __restrict__ wcat,
                         const float* __restrict__ xin,
                         const float* __restrict__ b_hp, const float* __restrict__ b_res,
                         const float* __restrict__ b_mul,
                         float* __restrict__ out, float* __restrict__ filt_raw)
{
    __shared__ u16 As[64 * 152];         // 19,456 B
    __shared__ u16 Bs[6 * 132 * 24];     // 38,016 B

    const int pt  = blockIdx.x;          // 0..127
    const int n   = pt >> 5;
    const int y0  = (pt & 31) * 4;
    const int co0 = blockIdx.y * 64;

    const int tid  = threadIdx.x;
    const int wv   = tid >> 6;
    const int lane = tid & 63;
    const int l31  = lane & 31;
    const int lh   = lane >> 5;

    for (int i = tid; i < 6*132*24/2; i += 256) ((int*)Bs)[i] = 0;

    f32x16 acc[2][4];
    #pragma unroll
    for (int cf = 0; cf < 2; ++cf)
        #pragma unroll
        for (int p = 0; p < 4; ++p)
            #pragma unroll
            for (int e = 0; e < 16; ++e) acc[cf][p][e] = 0.f;

    const u16* wbase = wcat + (long)co0 * 2304;

    // loop-invariant staging coordinates
    const u16* asrc[9]; u16* adst[9];
    #pragma unroll
    for (int r = 0; r < 9; ++r) {
        int l  = tid + 256*r;
        int co = l / 36, u = l - co*36;
        int tap = u >> 2, ciq = u & 3;
        asrc[r] = wbase + co*2304 + tap*256 + ciq*4;
        adst[r] = As + co*152 + tap*16 + ciq*4;
    }
    const u16* bsrc[3]; u16* bdst[3]; bool bvld[3];
    #pragma unroll
    for (int rr = 0; rr < 3; ++rr) {
        int l = tid + 256*rr;
        int q = l & 3, t = l >> 2;
        int r = t >> 5, g = t & 31;
        int yy = y0 - 1 + r;
        bvld[rr] = (yy >= 0 && yy < H);
        int yc = bvld[rr] ? yy : 0;
        bsrc[rr] = comp + ((long)n*C + q*4)*HW + yc*W + g*4;
        bdst[rr] = Bs + (r*132 + g*4 + 1)*24 + q*4;
    }

    __syncthreads();                      // Bs zero-fill visible

    // prologue prefetch: chunk 0 B into registers
    ushort4 pb[3][4];
    #pragma unroll
    for (int rr = 0; rr < 3; ++rr)
        if (bvld[rr]) {
            const u16* s = bsrc[rr];
            pb[rr][0] = *(const ushort4*)(s);
            pb[rr][1] = *(const ushort4*)(s + HW);
            pb[rr][2] = *(const ushort4*)(s + 2*HW);
            pb[rr][3] = *(const ushort4*)(s + 3*HW);
        }

    for (int c = 0; c < 16; ++c) {
        const int c0 = c * 16;
        // A stage (direct load->LDS; L2-hot)
        #pragma unroll
        for (int r = 0; r < 9; ++r) {
            ushort4 v = *(const ushort4*)(asrc[r] + c0);
            *(ushort4*)(adst[r]) = v;
        }
        // B stage: write prefetched regs (transposed)
        #pragma unroll
        for (int rr = 0; rr < 3; ++rr)
            if (bvld[rr]) {
                u16* d = bdst[rr];
                *(ushort4*)(d)      = make_ushort4(pb[rr][0].x, pb[rr][1].x, pb[rr][2].x, pb[rr][3].x);
                *(ushort4*)(d + 24) = make_ushort4(pb[rr][0].y, pb[rr][1].y, pb[rr][2].y, pb[rr][3].y);
                *(ushort4*)(d + 48) = make_ushort4(pb[rr][0].z, pb[rr][1].z, pb[rr][2].z, pb[rr][3].z);
                *(ushort4*)(d + 72) = make_ushort4(pb[rr][0].w, pb[rr][1].w, pb[rr][2].w, pb[rr][3].w);
            }
        __syncthreads();
        // prefetch next chunk's B (in flight across the MFMA phase)
        if (c < 15) {
            const long koff = (long)(c0 + 16) * HW;
            #pragma unroll
            for (int rr = 0; rr < 3; ++rr)
                if (bvld[rr]) {
                    const u16* s = bsrc[rr] + koff;
                    pb[rr][0] = *(const ushort4*)(s);
                    pb[rr][1] = *(const ushort4*)(s + HW);
                    pb[rr][2] = *(const ushort4*)(s + 2*HW);
                    pb[rr][3] = *(const ushort4*)(s + 3*HW);
                }
        }
        // MFMA: per tap 2 A-frags x 4 B-frags
        #pragma unroll
        for (int tap = 0; tap < 9; ++tap) {
            const int kh = tap / 3, kw = tap - kh*3;
            bf16x8 a0 = *(const bf16x8*)(As + (l31      )*152 + tap*16 + lh*8);
            bf16x8 a1 = *(const bf16x8*)(As + (l31 + 32 )*152 + tap*16 + lh*8);
            #pragma unroll
            for (int p = 0; p < 4; ++p) {
                bf16x8 bfr = *(const bf16x8*)(Bs + ((wv+kh)*132 + p*32 + l31 + kw)*24 + lh*8);
                acc[0][p] = __builtin_amdgcn_mfma_f32_32x32x16_bf16(a0, bfr, acc[0][p], 0, 0, 0);
                acc[1][p] = __builtin_amdgcn_mfma_f32_32x32x16_bf16(a1, bfr, acc[1][p], 0, 0, 0);
            }
        }
        __syncthreads();
    }

    // epilogue: D col = lane&31 (pos), row = (reg&3)+8*(reg>>2)+4*(lane>>5) (co)
    const int yrow = y0 + wv;
    #pragma unroll
    for (int cf = 0; cf < 2; ++cf) {
        #pragma unroll
        for (int p = 0; p < 4; ++p) {
            #pragma unroll
            for (int reg = 0; reg < 16; ++reg) {
                int row = (reg & 3) + 8*(reg >> 2) + 4*lh;
                int co  = co0 + cf*32 + row;
                int xx  = p*32 + l31;
                float v = acc[cf][p][reg];
                if (co < 9) {
                    filt_raw[((long)n*9 + co)*HW + yrow*W + xx] = v + b_hp[co];
                } else if (co < 265) {
                    int c = co - 9;
                    long idx = (long)n*CHW + (long)c*HW + yrow*W + xx;
                    out[(long)TOT + idx] = xin[idx] + v + b_res[c];
                } else if (co < 521) {
                    int c = co - 265;
                    long idx = (long)n*CHW + (long)c*HW + yrow*W + xx;
                    out[2L*TOT + idx] = xin[idx] * (v + b_mul[c]);
                }
            }
        }
    }
}

// ---------------------------------------------------------------------------
// K3: softmax*hamming renorm + 3x3 carafe + feat_hp = x - carafe (float4)
// block = (n,y); threads: 32 pos-groups(x4) x 8 ch-slices(x32)
// ---------------------------------------------------------------------------
__global__ __launch_bounds__(256)
void carafe_hp_kernel(const float* __restrict__ x, const float* __restrict__ filt_raw,
                      const float* __restrict__ ham, float* __restrict__ out)
{
    const int pt = blockIdx.x;
    const int n  = pt >> 7;
    const int y  = pt & 127;
    const int pg = threadIdx.x & 31;
    const int cs = threadIdx.x >> 5;
    const int x0 = pg * 4;

    float4 wt[9];
    {
        const float* fr = filt_raw + (long)n*9*HW + y*W + x0;
        #pragma unroll
        for (int t = 0; t < 9; ++t) wt[t] = *(const float4*)(fr + t*HW);
        float4 mx = wt[0];
        #pragma unroll
        for (int t = 1; t < 9; ++t) {
            mx.x = fmaxf(mx.x, wt[t].x); mx.y = fmaxf(mx.y, wt[t].y);
            mx.z = fmaxf(mx.z, wt[t].z); mx.w = fmaxf(mx.w, wt[t].w);
        }
        float4 s = make_float4(0,0,0,0);
        #pragma unroll
        for (int t = 0; t < 9; ++t) {
            float hm = ham[t];
            wt[t].x = expf(wt[t].x - mx.x) * hm; s.x += wt[t].x;
            wt[t].y = expf(wt[t].y - mx.y) * hm; s.y += wt[t].y;
            wt[t].z = expf(wt[t].z - mx.z) * hm; s.z += wt[t].z;
            wt[t].w = expf(wt[t].w - mx.w) * hm; s.w += wt[t].w;
        }
        float4 inv = make_float4(1.f/s.x, 1.f/s.y, 1.f/s.z, 1.f/s.w);
        #pragma unroll
        for (int t = 0; t < 9; ++t) {
            wt[t].x *= inv.x; wt[t].y *= inv.y; wt[t].z *= inv.z; wt[t].w *= inv.w;
        }
    }

    const float* xb = x   + (long)n*CHW + (long)y*W + x0;
    float*       ob = out + (long)n*CHW + (long)y*W + x0;

    for (int i = 0; i < 32; ++i) {
        int c = cs*32 + i;
        const float* xc = xb + (long)c*HW;
        float rr[3][6];
        #pragma unroll
        for (int dh = 0; dh < 3; ++dh) {
            int yy = y - 1 + dh;
            if (yy >= 0 && yy < H) {
                const float* p = xc + (dh-1)*W;
                float4 v = *(const float4*)p;
                rr[dh][0] = (x0 > 0)     ? p[-1] : 0.f;
                rr[dh][1] = v.x; rr[dh][2] = v.y; rr[dh][3] = v.z; rr[dh][4] = v.w;
                rr[dh][5] = (x0 + 4 < W) ? p[4]  : 0.f;
            } else {
                #pragma unroll
                for (int j = 0; j < 6; ++j) rr[dh][j] = 0.f;
            }
        }
        float4 a = make_float4(0,0,0,0);
        #pragma unroll
        for (int dh = 0; dh < 3; ++dh)
            #pragma unroll
            for (int kw = 0; kw < 3; ++kw) {
                float4 wv = wt[dh*3+kw];
                a.x += wv.x * rr[dh][kw];
                a.y += wv.y * rr[dh][kw+1];
                a.z += wv.z * rr[dh][kw+2];
                a.w += wv.w * rr[dh][kw+3];
            }
        float4 o;
        o.x = rr[1][1] - a.x; o.y = rr[1][2] - a.y;
        o.z = rr[1][3] - a.z; o.w = rr[1][4] - a.w;
        *(float4*)(ob + (long)c*HW) = o;
    }
}

// ---------------------------------------------------------------------------
extern "C" void kernel_launch(void* const* d_in, const int* in_sizes, int n_in,
                              void* d_out, int out_size, void* d_ws, size_t ws_size,
                              hipStream_t stream)
{
    const float* x      = (const float*)d_in[0];
    const float* w_comp = (const float*)d_in[1];
    const float* b_comp = (const float*)d_in[2];
    const float* w_hp   = (const float*)d_in[3];
    const float* b_hp   = (const float*)d_in[4];
    const float* w_res  = (const float*)d_in[5];
    const float* b_res  = (const float*)d_in[6];
    const float* w_mul  = (const float*)d_in[7];
    const float* b_mul  = (const float*)d_in[8];
    const float* ham    = (const float*)d_in[9];
    float* out = (float*)d_out;

    u16*   comp = (u16*)d_ws;                                         // 33,554,432 B
    float* filt = (float*)((char*)d_ws + (size_t)TOT*2);              //  2,359,296 B
    u16*   wcat = (u16*)((char*)d_ws + (size_t)TOT*2 + 2359296);      //  2,654,208 B
    u16*   wbf  = (u16*)((char*)d_ws + (size_t)TOT*2 + 2359296 + 2654208); // 131,072 B

    const int NW = 576*2304;
    prep_w_kernel<<<(NW + 65536 + 255)/256, 256, 0, stream>>>(w_hp, w_res, w_mul, w_comp, wcat, wbf);
    conv1x1_mfma_kernel<<<dim3(256, 4), 256, 0, stream>>>(x, wbf, b_comp, comp);
    conv3x3_mfma_kernel<<<dim3(NIMG*H/4, 9), 256, 0, stream>>>(
        comp, wcat, x, b_hp, b_res, b_mul, out, filt);
    carafe_hp_kernel<<<NIMG*H, 256, 0, stream>>>(x, filt, ham, out);
}